// Round 9
// baseline (365.109 us; speedup 1.0000x reference)
//
#include <hip/hip_runtime.h>
#include <float.h>

#define BB 16
#define NN 4096
#define CC 64
#define KNN 32
#define NSLICE 16   // select slices per query
#define SSZ 256     // NN / NSLICE
#define CKEEP 8     // kept per slice
#define NQ 65536

// ===========================================================================
// KNN via packed-key select (R13) + 2-src sort network (R15) + fetch
// amortization (R18/R18b). Reference arithmetic VARIANT V2:
//   dot = fma(z,z', fma(y,y', x*x'));  xx = ((x*x + y*y) + z*z)  [rn, no fma]
//   pd  = ((dot+dot) - qxx) - xx_c
//   key = (~bits(min(pd,0)) & 0xFFFFF000) | (4095 - idx)
//
// R17 post-mortem: select pinned at 63-65 cyc/pt across 3 load paths, 2
// compute structures, 2 block sizes. Shared invariant: ONE 16B fetch per
// point per WAVE on a per-CU shared pipe (DS: 4.19e6 b128 / 256 CU x 12cyc
// = 82us; SMEM x16: ~109us) + VALU ~60us. R18 breaks the invariant:
//  (a) 2 queries/lane (q, q+256): each fetched point used twice -> DS/2.
//  (b) SoA LDS (x[],y[],z[],nxx[] as f32x2) + v_pk_fma_f32 dual-fp32 dist:
//      2 points/instr. Bit-exact: query coords pre-doubled (q2x=qx+qx,
//      exact) so the pk chain computes 2*dot with roundings that commute
//      with the *2 binade shift; then +(-qxx), +(-xx) left-assoc == V2.
//      Keys byte-identical to R15 -> merge/certs/fallback untouched.
// R18b fix: VOP3P packed-fp32 requires ALL operands as 64b VGPR pairs --
// scalar query consts broadcast to {s,s} pairs; plain pair-operand asm.
// Per point-query: 2.5 pk + 4 scalar + 8.75 network = 14.25 VALU (-19%).
// Certificates ((a) strict 20-bit separation at rank 32/33, (b) slice
// exhaustion) -> compacted flag list -> exact wave-per-query radix
// fallback (full-precision keys, exact ties). Correct at any flag rate.
// ===========================================================================

typedef __attribute__((ext_vector_type(2))) float f32x2;

__device__ __forceinline__ int lane_rank(unsigned long long m) {
    return __builtin_amdgcn_mbcnt_hi((unsigned)(m >> 32),
           __builtin_amdgcn_mbcnt_lo((unsigned)m, 0u));
}

__device__ __forceinline__ unsigned umaxu(unsigned a, unsigned b) {
    return a > b ? a : b;   // v_max_u32
}
__device__ __forceinline__ unsigned uminu(unsigned a, unsigned b) {
    return a < b ? a : b;   // v_min_u32
}
// compare-exchange, descending: a gets max, b gets min (2 two-src ops)
#define CE(a, b) { unsigned _mx = umaxu(a, b); b = uminu(a, b); a = _mx; }

// packed dual-fp32 helpers; ALL operands are 64-bit VGPR pairs
__device__ __forceinline__ f32x2 pk_mul(f32x2 a, f32x2 b) {
    f32x2 d;
    asm("v_pk_mul_f32 %0, %1, %2" : "=v"(d) : "v"(a), "v"(b));
    return d;
}
__device__ __forceinline__ f32x2 pk_fma(f32x2 a, f32x2 b, f32x2 c) {
    f32x2 d;
    asm("v_pk_fma_f32 %0, %1, %2, %3" : "=v"(d) : "v"(a), "v"(b), "v"(c));
    return d;
}
__device__ __forceinline__ f32x2 pk_add(f32x2 a, f32x2 b) {
    f32x2 d;
    asm("v_pk_add_f32 %0, %1, %2" : "=v"(d) : "v"(a), "v"(b));
    return d;
}
__device__ __forceinline__ f32x2 bc2(float s) {
    f32x2 r; r[0] = s; r[1] = s; return r;
}

// --------------------------------------------------------------------------
// P: prep. SoA: gx,gy,gz = coords; gn = -xx (V2 rn formula). Resets flag_cnt.
// --------------------------------------------------------------------------
__global__ __launch_bounds__(256) void prep_kernel(
        const float* __restrict__ xyz, float* __restrict__ gx,
        float* __restrict__ gy, float* __restrict__ gz,
        float* __restrict__ gn, int* __restrict__ flag_cnt) {
#pragma clang fp contract(off)
    const int p = blockIdx.x * 256 + threadIdx.x;
    if (p == 0) flag_cnt[0] = 0;
    const int b = p >> 12;
    const int i = p & (NN - 1);
    const float* xb = xyz + (size_t)b * (3 * NN);
    float x = xb[i], y = xb[NN + i], z = xb[2 * NN + i];
    float xx = ((x * x) + (y * y)) + (z * z);  // rn (contract off)
    gx[p] = x; gy[p] = y; gz[p] = z; gn[p] = -xx;
}

// --------------------------------------------------------------------------
// A: select. grid 2048 = (b<<7)|(g8<<4)|s; 256 thr; 2 queries/lane
// (q0 = g8*512+tid, q1 = q0+256). Slice s staged as SoA f32x2 (4 KB).
// pk dual-fp32 dist (bit-exact V2), 8-pt 2-src network per query.
// --------------------------------------------------------------------------
__global__ __launch_bounds__(256) void knn_select_kernel(
        const float* __restrict__ gx, const float* __restrict__ gy,
        const float* __restrict__ gz, const float* __restrict__ gn,
        unsigned* __restrict__ val_buf) {
#pragma clang fp contract(off)
    __shared__ f32x2 lx2[128], ly2[128], lz2[128], ln2[128];
    const int tid = threadIdx.x;
    const int blk = blockIdx.x;
    const int s = blk & 15;
    const int g8 = (blk >> 4) & 7;
    const int b = blk >> 7;
    const int pbase = (b << 12) | (s << 8);

    ((float*)lx2)[tid] = gx[pbase + tid];
    ((float*)ly2)[tid] = gy[pbase + tid];
    ((float*)lz2)[tid] = gz[pbase + tid];
    ((float*)ln2)[tid] = gn[pbase + tid];

    const int q0 = (g8 << 9) | tid;      // in [g8*512, g8*512+256)
    const int q1 = q0 + 256;
    const int qb = b << 12;
    // query consts as broadcast pairs: doubled coords (exact), nqxx = gn
    const f32x2 Q2X0 = bc2(gx[qb + q0] + gx[qb + q0]);
    const f32x2 Q2Y0 = bc2(gy[qb + q0] + gy[qb + q0]);
    const f32x2 Q2Z0 = bc2(gz[qb + q0] + gz[qb + q0]);
    const f32x2 NQX0 = bc2(gn[qb + q0]);
    const f32x2 Q2X1 = bc2(gx[qb + q1] + gx[qb + q1]);
    const f32x2 Q2Y1 = bc2(gy[qb + q1] + gy[qb + q1]);
    const f32x2 Q2Z1 = bc2(gz[qb + q1] + gz[qb + q1]);
    const f32x2 NQX1 = bc2(gn[qb + q1]);
    __syncthreads();

    unsigned ha0=0,ha1=0,ha2=0,ha3=0,ha4=0,ha5=0,ha6=0,ha7=0;
    unsigned hb0=0,hb1=0,hb2=0,hb3=0,hb4=0,hb5=0,hb6=0,hb7=0;
    const unsigned ibase = 4095u - (unsigned)(s << 8);  // idxterm = ibase - j

// pd pair for 2 points vs one query; D0/D1 = packed keys.
//   t = ((2q . p) - qxx) - xx  computed as pk chain (bit-exact V2)
#define PDK(PX, PY, PZ, PN, QX, QY, QZ, NQX, JB, D0, D1) { \
    f32x2 t = pk_mul(PX, QX); \
    t = pk_fma(PY, QY, t); \
    t = pk_fma(PZ, QZ, t); \
    t = pk_add(t, NQX); \
    t = pk_add(t, PN); \
    float p0 = fminf(t[0], 0.0f), p1 = fminf(t[1], 0.0f); \
    D0 = (~__float_as_uint(p0) & 0xFFFFF000u) | (ibase - (unsigned)(JB)); \
    D1 = (~__float_as_uint(p1) & 0xFFFFF000u) | (ibase - (unsigned)(JB+1)); }

// sort8 desc (Batcher OEMS 19 CE) + half-clean + bitonic-merge8 (12 CE)
#define NET8(HP) \
    CE(k0,k1) CE(k2,k3) CE(k0,k2) CE(k1,k3) CE(k1,k2) \
    CE(k4,k5) CE(k6,k7) CE(k4,k6) CE(k5,k7) CE(k5,k6) \
    CE(k0,k4) CE(k1,k5) CE(k2,k6) CE(k3,k7) \
    CE(k2,k4) CE(k3,k5) \
    CE(k1,k2) CE(k3,k4) CE(k5,k6) \
    HP##0 = umaxu(HP##0, k7); HP##1 = umaxu(HP##1, k6); \
    HP##2 = umaxu(HP##2, k5); HP##3 = umaxu(HP##3, k4); \
    HP##4 = umaxu(HP##4, k3); HP##5 = umaxu(HP##5, k2); \
    HP##6 = umaxu(HP##6, k1); HP##7 = umaxu(HP##7, k0); \
    CE(HP##0,HP##4) CE(HP##1,HP##5) CE(HP##2,HP##6) CE(HP##3,HP##7) \
    CE(HP##0,HP##2) CE(HP##1,HP##3) CE(HP##4,HP##6) CE(HP##5,HP##7) \
    CE(HP##0,HP##1) CE(HP##2,HP##3) CE(HP##4,HP##5) CE(HP##6,HP##7)

    for (int j2 = 0; j2 < 128; j2 += 4) {   // 8 points per iteration
        f32x2 xa = lx2[j2], xb2 = lx2[j2+1], xc = lx2[j2+2], xd = lx2[j2+3];
        f32x2 ya = ly2[j2], yb = ly2[j2+1], yc = ly2[j2+2], yd = ly2[j2+3];
        f32x2 za = lz2[j2], zb = lz2[j2+1], zc = lz2[j2+2], zd = lz2[j2+3];
        f32x2 na = ln2[j2], nb = ln2[j2+1], nc = ln2[j2+2], nd = ln2[j2+3];
        const int jb = j2 << 1;
        {   // query 0
            unsigned k0,k1,k2,k3,k4,k5,k6,k7;
            PDK(xa, ya, za, na, Q2X0, Q2Y0, Q2Z0, NQX0, jb+0, k0, k1)
            PDK(xb2,yb, zb, nb, Q2X0, Q2Y0, Q2Z0, NQX0, jb+2, k2, k3)
            PDK(xc, yc, zc, nc, Q2X0, Q2Y0, Q2Z0, NQX0, jb+4, k4, k5)
            PDK(xd, yd, zd, nd, Q2X0, Q2Y0, Q2Z0, NQX0, jb+6, k6, k7)
            NET8(ha)
        }
        {   // query 1 (same fetched points)
            unsigned k0,k1,k2,k3,k4,k5,k6,k7;
            PDK(xa, ya, za, na, Q2X1, Q2Y1, Q2Z1, NQX1, jb+0, k0, k1)
            PDK(xb2,yb, zb, nb, Q2X1, Q2Y1, Q2Z1, NQX1, jb+2, k2, k3)
            PDK(xc, yc, zc, nc, Q2X1, Q2Y1, Q2Z1, NQX1, jb+4, k4, k5)
            PDK(xd, yd, zd, nd, Q2X1, Q2Y1, Q2Z1, NQX1, jb+6, k6, k7)
            NET8(hb)
        }
    }
#undef PDK
#undef NET8

    unsigned* vp0 = val_buf + (size_t)(s * CKEEP) * NQ + (qb | q0);
    unsigned* vp1 = val_buf + (size_t)(s * CKEEP) * NQ + (qb | q1);
#define ST(t, p0v, p1v) { vp0[(size_t)(t) * NQ] = p0v; vp1[(size_t)(t) * NQ] = p1v; }
    ST(0,ha0,hb0) ST(1,ha1,hb1) ST(2,ha2,hb2) ST(3,ha3,hb3)
    ST(4,ha4,hb4) ST(5,ha5,hb5) ST(6,ha6,hb6) ST(7,ha7,hb7)
#undef ST
}

// --------------------------------------------------------------------------
// B: merge. 64-thr blocks; stage 16x8=128 keys/query to LDS (stride 129);
// 33-step 16-head merge. First 32 picks -> idx_out directly
// (idx = 4095 - (key & 4095)). Certificates -> flag list.
// --------------------------------------------------------------------------
__global__ __launch_bounds__(64) void knn_merge_kernel(
        const unsigned* __restrict__ val_buf, int* __restrict__ idx_out,
        int* __restrict__ flag_list, int* __restrict__ flag_cnt) {
    __shared__ unsigned lv[64 * 129];  // 33 KB
    const int tid = threadIdx.x;
    const int qg = blockIdx.x * 64 + tid;
    unsigned* my = lv + tid * 129;
    for (int t = 0; t < 128; ++t) my[t] = val_buf[(size_t)t * NQ + qg];

    int p0=0,p1=0,p2=0,p3=0,p4=0,p5=0,p6=0,p7=0,
        p8=0,p9=0,p10=0,p11=0,p12=0,p13=0,p14=0,p15=0;
    unsigned v0 =my[0],  v1 =my[8],  v2 =my[16],  v3 =my[24];
    unsigned v4 =my[32], v5 =my[40], v6 =my[48],  v7 =my[56];
    unsigned v8 =my[64], v9 =my[72], v10=my[80],  v11=my[88];
    unsigned v12=my[96], v13=my[104],v14=my[112], v15=my[120];
    int* outp = idx_out + (size_t)qg * KNN;
    unsigned key32 = 0u, key33 = 0u;
    for (int step = 0; step < 33; ++step) {
        unsigned best = v0; int bp = 0;
        if (v1  > best) { best = v1;  bp = 1; }
        if (v2  > best) { best = v2;  bp = 2; }
        if (v3  > best) { best = v3;  bp = 3; }
        if (v4  > best) { best = v4;  bp = 4; }
        if (v5  > best) { best = v5;  bp = 5; }
        if (v6  > best) { best = v6;  bp = 6; }
        if (v7  > best) { best = v7;  bp = 7; }
        if (v8  > best) { best = v8;  bp = 8; }
        if (v9  > best) { best = v9;  bp = 9; }
        if (v10 > best) { best = v10; bp = 10; }
        if (v11 > best) { best = v11; bp = 11; }
        if (v12 > best) { best = v12; bp = 12; }
        if (v13 > best) { best = v13; bp = 13; }
        if (v14 > best) { best = v14; bp = 14; }
        if (v15 > best) { best = v15; bp = 15; }
        if (step == 32) { key33 = best; break; }
        outp[step] = 4095 - (int)(best & 4095u);
        if (step == 31) key32 = best;
        if      (bp==0)  { ++p0;  v0  = (p0 <8)?my[p0]      :0u; }
        else if (bp==1)  { ++p1;  v1  = (p1 <8)?my[8+p1]    :0u; }
        else if (bp==2)  { ++p2;  v2  = (p2 <8)?my[16+p2]   :0u; }
        else if (bp==3)  { ++p3;  v3  = (p3 <8)?my[24+p3]   :0u; }
        else if (bp==4)  { ++p4;  v4  = (p4 <8)?my[32+p4]   :0u; }
        else if (bp==5)  { ++p5;  v5  = (p5 <8)?my[40+p5]   :0u; }
        else if (bp==6)  { ++p6;  v6  = (p6 <8)?my[48+p6]   :0u; }
        else if (bp==7)  { ++p7;  v7  = (p7 <8)?my[56+p7]   :0u; }
        else if (bp==8)  { ++p8;  v8  = (p8 <8)?my[64+p8]   :0u; }
        else if (bp==9)  { ++p9;  v9  = (p9 <8)?my[72+p9]   :0u; }
        else if (bp==10) { ++p10; v10 = (p10<8)?my[80+p10]  :0u; }
        else if (bp==11) { ++p11; v11 = (p11<8)?my[88+p11]  :0u; }
        else if (bp==12) { ++p12; v12 = (p12<8)?my[96+p12]  :0u; }
        else if (bp==13) { ++p13; v13 = (p13<8)?my[104+p13] :0u; }
        else if (bp==14) { ++p14; v14 = (p14<8)?my[112+p14] :0u; }
        else             { ++p15; v15 = (p15<8)?my[120+p15] :0u; }
    }

    // certificates: (a) strict 20-bit separation at the 32/33 boundary;
    // (b) every slice's 8th kept key < key33 (merge saw the true top-33).
    bool flag = ((key32 >> 12) == (key33 >> 12));
    for (int sl = 0; sl < 16; ++sl)
        flag = flag || (my[sl * 8 + 7] >= key33);
    if (flag) {
        int pos = atomicAdd(flag_cnt, 1);
        flag_list[pos] = qg;
    }
}

// --------------------------------------------------------------------------
// B2: exact fallback, wave-per-query over the compacted flag list.
// Full-precision mono keys in 64 statically-indexed VGPRs; 32-step radix
// select -> exact 32nd key; indices via ballot compaction (index order,
// eq-ties take first `budget` -- exact reference tie semantics).
// --------------------------------------------------------------------------
__global__ __launch_bounds__(256) void knn_fallback_kernel(
        const float* __restrict__ xyz, const int* __restrict__ flag_list,
        const int* __restrict__ flag_cnt, int* __restrict__ idx_out) {
#pragma clang fp contract(off)
    const int nflag = flag_cnt[0];
    const int lane = threadIdx.x & 63;
    const int wid = (blockIdx.x * 256 + threadIdx.x) >> 6;
    const int nw = (gridDim.x * 256) >> 6;
    for (int w = wid; w < nflag; w += nw) {
        const int qg = flag_list[w];
        const int b = qg >> 12;
        const int q = qg & (NN - 1);
        const float* xb = xyz + (size_t)b * (3 * NN);
        const float qx = xb[q], qy = xb[NN + q], qz = xb[2 * NN + q];
        const float qxx = ((qx * qx) + (qy * qy)) + (qz * qz);
        const float nqxx = -qxx;

        unsigned key[64];
#pragma unroll
        for (int i = 0; i < 64; ++i) {
            const int j = (i << 6) | lane;
            float x = xb[j], y = xb[NN + j], z = xb[2 * NN + j];
            float xxc = ((x * x) + (y * y)) + (z * z);
            float dot = __builtin_fmaf(qz, z, __builtin_fmaf(qy, y, qx * x));
            float pd = __builtin_fmaf(2.0f, dot, nqxx) - xxc;
            unsigned u = __float_as_uint(pd);
            key[i] = u ^ (unsigned)(((int)u >> 31) | 0x80000000);
        }

        // largest t with #{key >= t} >= 32  ==  32nd-largest key
        unsigned cur = 0u;
        for (int bit = 31; bit >= 0; --bit) {
            const unsigned cand = cur | (1u << bit);
            int c = 0;
#pragma unroll
            for (int i = 0; i < 64; ++i) c += (key[i] >= cand) ? 1 : 0;
#pragma unroll
            for (int o = 32; o >= 1; o >>= 1) c += __shfl_xor(c, o, 64);
            if (c >= 32) cur = cand;  // uniform after butterfly
        }

        // exact gt/eq totals
        int ge = 0;
#pragma unroll
        for (int i = 0; i < 64; ++i) {
            ge += (key[i] > cur) ? 1 : 0;
            ge += (key[i] == cur) ? 0x10000 : 0;
        }
#pragma unroll
        for (int o = 32; o >= 1; o >>= 1) ge += __shfl_xor(ge, o, 64);
        const int gt_total = ge & 0xFFFF;
        const int budget = min(ge >> 16, 32 - gt_total);

        int* outp = idx_out + (size_t)qg * KNN;
        int slot = 0, neq = 0;
#pragma unroll
        for (int i = 0; i < 64; ++i) {
            const bool isgt = key[i] > cur;
            const bool iseq = key[i] == cur;
            const unsigned long long mgt = __ballot(isgt);
            const unsigned long long meq = __ballot(iseq);
            if (isgt) outp[slot + lane_rank(mgt)] = (i << 6) | lane;
            if (iseq) {
                const int r = neq + lane_rank(meq);
                if (r < budget) outp[gt_total + r] = (i << 6) | lane;
            }
            slot += __builtin_popcountll(mgt);
            neq += __builtin_popcountll(meq);
        }
    }
}

// --------------------------------------------------------------------------
// gather / finalize: unchanged. sigma: 1024 thr (R17).
// --------------------------------------------------------------------------
__global__ __launch_bounds__(256) void gather_minmax_kernel(
        const float* __restrict__ feats, const int* __restrict__ idx_in,
        float* __restrict__ mx_buf, float* __restrict__ mn_buf,
        double* __restrict__ partials) {
    const int tid = threadIdx.x;
    const int w = tid >> 6;
    const int lane = tid & 63;
    const int q = blockIdx.x * 4 + w;
    const int b = q >> 12;
    const float* fb = feats + (size_t)b * (NN * CC);
    const float center = feats[(size_t)q * CC + lane];
    const int* ip = idx_in + (size_t)q * KNN;

    float mx = -FLT_MAX, mn = FLT_MAX;
    double ss = 0.0;
#pragma unroll 4
    for (int k = 0; k < KNN; ++k) {
        int nb = ip[k];
        float v = fb[(size_t)nb * CC + lane];
        float off = v - center;
        mx = fmaxf(mx, off);
        mn = fminf(mn, off);
        double od = (double)off;
        ss = fma(od, od, ss);
    }
    mx_buf[(size_t)q * CC + lane] = mx;
    mn_buf[(size_t)q * CC + lane] = mn;

#pragma unroll
    for (int o = 32; o >= 1; o >>= 1) ss += __shfl_down(ss, o, 64);
    __shared__ double wsum[4];
    if (lane == 0) wsum[w] = ss;
    __syncthreads();
    if (tid == 0) partials[blockIdx.x] = (wsum[0] + wsum[1]) + (wsum[2] + wsum[3]);
}

__global__ __launch_bounds__(1024) void sigma_kernel(const double* __restrict__ partials,
                                                     float* __restrict__ sigma) {
    __shared__ double red[1024];
    double s = 0.0;
    for (int i = threadIdx.x; i < 16384; i += 1024) s += partials[i];
    red[threadIdx.x] = s;
    __syncthreads();
    for (int o = 512; o >= 1; o >>= 1) {
        if (threadIdx.x < o) red[threadIdx.x] += red[threadIdx.x + o];
        __syncthreads();
    }
    if (threadIdx.x == 0) sigma[0] = (float)(red[0] * (1.0 / 134217728.0));
}

__global__ __launch_bounds__(256) void finalize_kernel(
        const float* __restrict__ mx_buf, const float* __restrict__ mn_buf,
        const float* __restrict__ alpha, const float* __restrict__ beta,
        const float* __restrict__ sigma, float* __restrict__ out) {
#pragma clang fp contract(off)
    const int e = blockIdx.x * 256 + threadIdx.x;
    const int c = e & (CC - 1);
    const float s = sigma[0] + 1e-5f;
    const float a = alpha[c];
    const float bt = beta[c];
    const float off = (a >= 0.f) ? mx_buf[e] : mn_buf[e];
    const float t = off / s;
    out[e] = (t * a) + bt;
}

extern "C" void kernel_launch(void* const* d_in, const int* in_sizes, int n_in,
                              void* d_out, int out_size, void* d_ws, size_t ws_size,
                              hipStream_t stream) {
    (void)in_sizes; (void)n_in; (void)out_size; (void)ws_size;
    const float* xyz   = (const float*)d_in[0];  // [16,3,4096]
    const float* feats = (const float*)d_in[1];  // [16,4096,64]
    const float* alpha = (const float*)d_in[2];  // [64]
    const float* beta  = (const float*)d_in[3];  // [64]
    float* out = (float*)d_out;                  // [16,4096,64]

    char* ws = (char*)d_ws;
    // Lifetimes:
    //   val_buf   [0, 33,554,432)          select->merge(read); dead after.
    //   mx/mn     alias val region          written by gather (post-merge).
    //   idx_buf   [33,554,432, 41,943,040)  merge/fallback write, gather reads.
    //   flag_list [41,943,040, +256 KB)     merge->fallback.
    //   flag_cnt  42,205,184 (4 B)
    //   gx/gy/gz/gn [42,205,248, +1 MB)     prep->select (SoA); dead after.
    //   partials  alias gx start            written by gather (post-select).
    //   sigma     43,254,784
    unsigned* val_buf  = (unsigned*)ws;
    float*    mx_buf   = (float*)ws;                  // [0, 16.78M)
    float*    mn_buf   = (float*)(ws + 16777216);     // [16.78M, 33.55M)
    int*      idx_buf  = (int*)(ws + 33554432);
    int*      flag_list= (int*)(ws + 41943040);
    int*      flag_cnt = (int*)(ws + 42205184);
    float*    gx       = (float*)(ws + 42205248);     // 256 KB each
    float*    gy       = (float*)(ws + 42467392);
    float*    gz       = (float*)(ws + 42729536);
    float*    gn       = (float*)(ws + 42991680);
    double*   partials = (double*)(ws + 42205248);    // alias gx (dead)
    float*    sigma    = (float*)(ws + 43254784);

    prep_kernel<<<NQ / 256, 256, 0, stream>>>(xyz, gx, gy, gz, gn, flag_cnt);
    knn_select_kernel<<<BB * 8 * NSLICE, 256, 0, stream>>>(gx, gy, gz, gn,
                                                           val_buf);
    knn_merge_kernel<<<NQ / 64, 64, 0, stream>>>(val_buf, idx_buf,
                                                 flag_list, flag_cnt);
    knn_fallback_kernel<<<256, 256, 0, stream>>>(xyz, flag_list, flag_cnt,
                                                 idx_buf);
    gather_minmax_kernel<<<NQ / 4, 256, 0, stream>>>(feats, idx_buf, mx_buf,
                                                     mn_buf, partials);
    sigma_kernel<<<1, 1024, 0, stream>>>(partials, sigma);
    finalize_kernel<<<(NQ * CC) / 256, 256, 0, stream>>>(mx_buf, mn_buf, alpha,
                                                         beta, sigma, out);
}

// Round 10
// 339.271 us; speedup vs baseline: 1.0762x; 1.0762x over previous
//
#include <hip/hip_runtime.h>
#include <float.h>

#define BB 16
#define NN 4096
#define CC 64
#define KNN 32
#define NSLICE 16   // select slices per query
#define SSZ 256     // NN / NSLICE
#define CKEEP 8     // kept per slice
#define NQ 65536

// ===========================================================================
// KNN via packed-key select (R13) -- R19 reverts select to the measured-best
// R13 structure (med3 chain + float4 LDS, 108us) after R14-R18 established
// that every alternative (s_load x4/x16, 2-src network, 1024-thr, pk SoA)
// is neutral-to-worse. Keeps the validated clamped-key math (R14-R16).
// Reference arithmetic VARIANT V2:
//   dot = fma(z,z', fma(y,y', x*x'));  xx = ((x*x + y*y) + z*z)  [rn, no fma]
//   pd  = fma(2, dot, -qxx) - xx_c    [== ((dot+dot)-qxx)-xx_c bitwise]
//   key = (~bits(min(pd,0)) & 0xFFFFF000) | (4095 - idx)
// Clamp safety: only near-zero positive pds (self-point jitter) collapse;
// boundary collisions have equal 20-bit prefixes -> certificate (a) flags
// -> exact fallback. Certificates: (a) strict 20-bit separation at rank
// 32/33, (b) slice exhaustion (8th kept >= key33). Violations -> compacted
// flag list -> exact wave-per-query radix fallback (full-precision keys,
// exact tie-by-lowest-index). Correct at any flag rate.
// ===========================================================================

__device__ __forceinline__ int lane_rank(unsigned long long m) {
    return __builtin_amdgcn_mbcnt_hi((unsigned)(m >> 32),
           __builtin_amdgcn_mbcnt_lo((unsigned)m, 0u));
}

__device__ __forceinline__ unsigned med3u(unsigned a, unsigned b, unsigned c) {
    unsigned d;
    asm("v_med3_u32 %0, %1, %2, %3" : "=v"(d) : "v"(a), "v"(b), "v"(c));
    return d;
}

// 8-deep descending insert on u32 keys (h00 >= h01 >= ... >= h07)
#define UCHAIN8 \
  h07=med3u(ky,h07,h06); h06=med3u(ky,h06,h05); h05=med3u(ky,h05,h04); \
  h04=med3u(ky,h04,h03); h03=med3u(ky,h03,h02); h02=med3u(ky,h02,h01); \
  h01=med3u(ky,h01,h00); h00=(h00>ky)?h00:ky;

// --------------------------------------------------------------------------
// P: prep. pts4[b*4096+i] = (x,y,z,xx), V2 rn formula; resets flag_cnt.
// --------------------------------------------------------------------------
__global__ __launch_bounds__(256) void prep_kernel(
        const float* __restrict__ xyz, float4* __restrict__ pts4,
        int* __restrict__ flag_cnt) {
#pragma clang fp contract(off)
    const int p = blockIdx.x * 256 + threadIdx.x;
    if (p == 0) flag_cnt[0] = 0;
    const int b = p >> 12;
    const int i = p & (NN - 1);
    const float* xb = xyz + (size_t)b * (3 * NN);
    float x = xb[i], y = xb[NN + i], z = xb[2 * NN + i];
    float xx = ((x * x) + (y * y)) + (z * z);  // rn (contract off)
    pts4[p] = make_float4(x, y, z, xx);
}

// --------------------------------------------------------------------------
// A: select. grid 4096 = (b<<8)|(g<<4)|s, 256 thr = 256 queries. LDS 4 KB.
// Keeps per-slice top-8 PACKED keys (desc), stored t=0..7.  (R13 structure)
// --------------------------------------------------------------------------
__global__ __launch_bounds__(256) void knn_select_kernel(
        const float4* __restrict__ pts4, unsigned* __restrict__ val_buf) {
#pragma clang fp contract(off)
    __shared__ float4 pts[SSZ];
    const int tid = threadIdx.x;
    const int blk = blockIdx.x;
    const int s = blk & 15;
    const int g = (blk >> 4) & 15;
    const int b = blk >> 8;
    const float4* pb = pts4 + (b << 12);

    pts[tid] = pb[(s << 8) | tid];  // SSZ == blockDim
    const int q = (g << 8) | tid;
    const float4 qp = pb[q];
    const float qx = qp.x, qy = qp.y, qz = qp.z;
    const float nqxx = -qp.w;
    __syncthreads();

    unsigned h00=0,h01=0,h02=0,h03=0,h04=0,h05=0,h06=0,h07=0;
    const unsigned ibase = 4095u - (unsigned)(s << 8);  // idxterm = ibase - j
#pragma unroll 4
    for (int j = 0; j < SSZ; ++j) {
        float4 cp = pts[j];
        float dot = __builtin_fmaf(qz, cp.z, __builtin_fmaf(qy, cp.y, qx * cp.x));
        float pd = __builtin_fmaf(2.0f, dot, nqxx) - cp.w;
        pd = fminf(pd, 0.0f);                  // all pd <= 0 -> mono = ~u
        unsigned ky = (~__float_as_uint(pd) & 0xFFFFF000u)
                      | (ibase - (unsigned)j);
        UCHAIN8
    }

    const int qg = (b << 12) | q;
    unsigned* vp = val_buf + (size_t)(s * CKEEP) * NQ + qg;  // desc t=0..7
#define ST(t, ht) vp[(size_t)(t) * NQ] = ht;
    ST(0,h00) ST(1,h01) ST(2,h02) ST(3,h03)
    ST(4,h04) ST(5,h05) ST(6,h06) ST(7,h07)
#undef ST
}

// --------------------------------------------------------------------------
// B: merge. 64-thr blocks; stage 16x8=128 keys/query to LDS (stride 129);
// 33-step 16-head merge. First 32 picks -> idx_out directly
// (idx = 4095 - (key & 4095)). Certificates -> flag list.
// --------------------------------------------------------------------------
__global__ __launch_bounds__(64) void knn_merge_kernel(
        const unsigned* __restrict__ val_buf, int* __restrict__ idx_out,
        int* __restrict__ flag_list, int* __restrict__ flag_cnt) {
    __shared__ unsigned lv[64 * 129];  // 33 KB
    const int tid = threadIdx.x;
    const int qg = blockIdx.x * 64 + tid;
    unsigned* my = lv + tid * 129;
    for (int t = 0; t < 128; ++t) my[t] = val_buf[(size_t)t * NQ + qg];

    int p0=0,p1=0,p2=0,p3=0,p4=0,p5=0,p6=0,p7=0,
        p8=0,p9=0,p10=0,p11=0,p12=0,p13=0,p14=0,p15=0;
    unsigned v0 =my[0],  v1 =my[8],  v2 =my[16],  v3 =my[24];
    unsigned v4 =my[32], v5 =my[40], v6 =my[48],  v7 =my[56];
    unsigned v8 =my[64], v9 =my[72], v10=my[80],  v11=my[88];
    unsigned v12=my[96], v13=my[104],v14=my[112], v15=my[120];
    int* outp = idx_out + (size_t)qg * KNN;
    unsigned key32 = 0u, key33 = 0u;
    for (int step = 0; step < 33; ++step) {
        unsigned best = v0; int bp = 0;
        if (v1  > best) { best = v1;  bp = 1; }
        if (v2  > best) { best = v2;  bp = 2; }
        if (v3  > best) { best = v3;  bp = 3; }
        if (v4  > best) { best = v4;  bp = 4; }
        if (v5  > best) { best = v5;  bp = 5; }
        if (v6  > best) { best = v6;  bp = 6; }
        if (v7  > best) { best = v7;  bp = 7; }
        if (v8  > best) { best = v8;  bp = 8; }
        if (v9  > best) { best = v9;  bp = 9; }
        if (v10 > best) { best = v10; bp = 10; }
        if (v11 > best) { best = v11; bp = 11; }
        if (v12 > best) { best = v12; bp = 12; }
        if (v13 > best) { best = v13; bp = 13; }
        if (v14 > best) { best = v14; bp = 14; }
        if (v15 > best) { best = v15; bp = 15; }
        if (step == 32) { key33 = best; break; }
        outp[step] = 4095 - (int)(best & 4095u);
        if (step == 31) key32 = best;
        if      (bp==0)  { ++p0;  v0  = (p0 <8)?my[p0]      :0u; }
        else if (bp==1)  { ++p1;  v1  = (p1 <8)?my[8+p1]    :0u; }
        else if (bp==2)  { ++p2;  v2  = (p2 <8)?my[16+p2]   :0u; }
        else if (bp==3)  { ++p3;  v3  = (p3 <8)?my[24+p3]   :0u; }
        else if (bp==4)  { ++p4;  v4  = (p4 <8)?my[32+p4]   :0u; }
        else if (bp==5)  { ++p5;  v5  = (p5 <8)?my[40+p5]   :0u; }
        else if (bp==6)  { ++p6;  v6  = (p6 <8)?my[48+p6]   :0u; }
        else if (bp==7)  { ++p7;  v7  = (p7 <8)?my[56+p7]   :0u; }
        else if (bp==8)  { ++p8;  v8  = (p8 <8)?my[64+p8]   :0u; }
        else if (bp==9)  { ++p9;  v9  = (p9 <8)?my[72+p9]   :0u; }
        else if (bp==10) { ++p10; v10 = (p10<8)?my[80+p10]  :0u; }
        else if (bp==11) { ++p11; v11 = (p11<8)?my[88+p11]  :0u; }
        else if (bp==12) { ++p12; v12 = (p12<8)?my[96+p12]  :0u; }
        else if (bp==13) { ++p13; v13 = (p13<8)?my[104+p13] :0u; }
        else if (bp==14) { ++p14; v14 = (p14<8)?my[112+p14] :0u; }
        else             { ++p15; v15 = (p15<8)?my[120+p15] :0u; }
    }

    // certificates: (a) strict 20-bit separation at the 32/33 boundary;
    // (b) every slice's 8th kept key < key33 (merge saw the true top-33).
    bool flag = ((key32 >> 12) == (key33 >> 12));
    for (int sl = 0; sl < 16; ++sl)
        flag = flag || (my[sl * 8 + 7] >= key33);
    if (flag) {
        int pos = atomicAdd(flag_cnt, 1);
        flag_list[pos] = qg;
    }
}

// --------------------------------------------------------------------------
// B2: exact fallback, wave-per-query over the compacted flag list.
// Full-precision mono keys in 64 statically-indexed VGPRs; 32-step radix
// select -> exact 32nd key; indices via ballot compaction (index order,
// eq-ties take first `budget` -- exact reference tie semantics).
// --------------------------------------------------------------------------
__global__ __launch_bounds__(256) void knn_fallback_kernel(
        const float* __restrict__ xyz, const int* __restrict__ flag_list,
        const int* __restrict__ flag_cnt, int* __restrict__ idx_out) {
#pragma clang fp contract(off)
    const int nflag = flag_cnt[0];
    const int lane = threadIdx.x & 63;
    const int wid = (blockIdx.x * 256 + threadIdx.x) >> 6;
    const int nw = (gridDim.x * 256) >> 6;
    for (int w = wid; w < nflag; w += nw) {
        const int qg = flag_list[w];
        const int b = qg >> 12;
        const int q = qg & (NN - 1);
        const float* xb = xyz + (size_t)b * (3 * NN);
        const float qx = xb[q], qy = xb[NN + q], qz = xb[2 * NN + q];
        const float qxx = ((qx * qx) + (qy * qy)) + (qz * qz);
        const float nqxx = -qxx;

        unsigned key[64];
#pragma unroll
        for (int i = 0; i < 64; ++i) {
            const int j = (i << 6) | lane;
            float x = xb[j], y = xb[NN + j], z = xb[2 * NN + j];
            float xxc = ((x * x) + (y * y)) + (z * z);
            float dot = __builtin_fmaf(qz, z, __builtin_fmaf(qy, y, qx * x));
            float pd = __builtin_fmaf(2.0f, dot, nqxx) - xxc;
            unsigned u = __float_as_uint(pd);
            key[i] = u ^ (unsigned)(((int)u >> 31) | 0x80000000);
        }

        // largest t with #{key >= t} >= 32  ==  32nd-largest key
        unsigned cur = 0u;
        for (int bit = 31; bit >= 0; --bit) {
            const unsigned cand = cur | (1u << bit);
            int c = 0;
#pragma unroll
            for (int i = 0; i < 64; ++i) c += (key[i] >= cand) ? 1 : 0;
#pragma unroll
            for (int o = 32; o >= 1; o >>= 1) c += __shfl_xor(c, o, 64);
            if (c >= 32) cur = cand;  // uniform after butterfly
        }

        // exact gt/eq totals
        int ge = 0;
#pragma unroll
        for (int i = 0; i < 64; ++i) {
            ge += (key[i] > cur) ? 1 : 0;
            ge += (key[i] == cur) ? 0x10000 : 0;
        }
#pragma unroll
        for (int o = 32; o >= 1; o >>= 1) ge += __shfl_xor(ge, o, 64);
        const int gt_total = ge & 0xFFFF;
        const int budget = min(ge >> 16, 32 - gt_total);

        int* outp = idx_out + (size_t)qg * KNN;
        int slot = 0, neq = 0;
#pragma unroll
        for (int i = 0; i < 64; ++i) {
            const bool isgt = key[i] > cur;
            const bool iseq = key[i] == cur;
            const unsigned long long mgt = __ballot(isgt);
            const unsigned long long meq = __ballot(iseq);
            if (isgt) outp[slot + lane_rank(mgt)] = (i << 6) | lane;
            if (iseq) {
                const int r = neq + lane_rank(meq);
                if (r < budget) outp[gt_total + r] = (i << 6) | lane;
            }
            slot += __builtin_popcountll(mgt);
            neq += __builtin_popcountll(meq);
        }
    }
}

// --------------------------------------------------------------------------
// gather / finalize: unchanged. sigma: 1024 thr (R17).
// --------------------------------------------------------------------------
__global__ __launch_bounds__(256) void gather_minmax_kernel(
        const float* __restrict__ feats, const int* __restrict__ idx_in,
        float* __restrict__ mx_buf, float* __restrict__ mn_buf,
        double* __restrict__ partials) {
    const int tid = threadIdx.x;
    const int w = tid >> 6;
    const int lane = tid & 63;
    const int q = blockIdx.x * 4 + w;
    const int b = q >> 12;
    const float* fb = feats + (size_t)b * (NN * CC);
    const float center = feats[(size_t)q * CC + lane];
    const int* ip = idx_in + (size_t)q * KNN;

    float mx = -FLT_MAX, mn = FLT_MAX;
    double ss = 0.0;
#pragma unroll 4
    for (int k = 0; k < KNN; ++k) {
        int nb = ip[k];
        float v = fb[(size_t)nb * CC + lane];
        float off = v - center;
        mx = fmaxf(mx, off);
        mn = fminf(mn, off);
        double od = (double)off;
        ss = fma(od, od, ss);
    }
    mx_buf[(size_t)q * CC + lane] = mx;
    mn_buf[(size_t)q * CC + lane] = mn;

#pragma unroll
    for (int o = 32; o >= 1; o >>= 1) ss += __shfl_down(ss, o, 64);
    __shared__ double wsum[4];
    if (lane == 0) wsum[w] = ss;
    __syncthreads();
    if (tid == 0) partials[blockIdx.x] = (wsum[0] + wsum[1]) + (wsum[2] + wsum[3]);
}

__global__ __launch_bounds__(1024) void sigma_kernel(const double* __restrict__ partials,
                                                     float* __restrict__ sigma) {
    __shared__ double red[1024];
    double s = 0.0;
    for (int i = threadIdx.x; i < 16384; i += 1024) s += partials[i];
    red[threadIdx.x] = s;
    __syncthreads();
    for (int o = 512; o >= 1; o >>= 1) {
        if (threadIdx.x < o) red[threadIdx.x] += red[threadIdx.x + o];
        __syncthreads();
    }
    if (threadIdx.x == 0) sigma[0] = (float)(red[0] * (1.0 / 134217728.0));
}

__global__ __launch_bounds__(256) void finalize_kernel(
        const float* __restrict__ mx_buf, const float* __restrict__ mn_buf,
        const float* __restrict__ alpha, const float* __restrict__ beta,
        const float* __restrict__ sigma, float* __restrict__ out) {
#pragma clang fp contract(off)
    const int e = blockIdx.x * 256 + threadIdx.x;
    const int c = e & (CC - 1);
    const float s = sigma[0] + 1e-5f;
    const float a = alpha[c];
    const float bt = beta[c];
    const float off = (a >= 0.f) ? mx_buf[e] : mn_buf[e];
    const float t = off / s;
    out[e] = (t * a) + bt;
}

extern "C" void kernel_launch(void* const* d_in, const int* in_sizes, int n_in,
                              void* d_out, int out_size, void* d_ws, size_t ws_size,
                              hipStream_t stream) {
    (void)in_sizes; (void)n_in; (void)out_size; (void)ws_size;
    const float* xyz   = (const float*)d_in[0];  // [16,3,4096]
    const float* feats = (const float*)d_in[1];  // [16,4096,64]
    const float* alpha = (const float*)d_in[2];  // [64]
    const float* beta  = (const float*)d_in[3];  // [64]
    float* out = (float*)d_out;                  // [16,4096,64]

    char* ws = (char*)d_ws;
    // Lifetimes:
    //   val_buf   [0, 33,554,432)          select->merge(read); dead after.
    //   mx/mn     alias val region          written by gather (post-merge).
    //   idx_buf   [33,554,432, 41,943,040)  merge/fallback write, gather reads.
    //   flag_list [41,943,040, +256 KB)     merge->fallback.
    //   flag_cnt  42,205,184 (4 B)
    //   pts4      [42,205,248, +1 MB)       prep->select; dead after select.
    //   partials  alias pts4 start          written by gather (post-select).
    //   sigma     43,254,784
    unsigned* val_buf  = (unsigned*)ws;
    float*    mx_buf   = (float*)ws;                  // [0, 16.78M)
    float*    mn_buf   = (float*)(ws + 16777216);     // [16.78M, 33.55M)
    int*      idx_buf  = (int*)(ws + 33554432);
    int*      flag_list= (int*)(ws + 41943040);
    int*      flag_cnt = (int*)(ws + 42205184);
    float4*   pts4     = (float4*)(ws + 42205248);    // 64B-aligned
    double*   partials = (double*)(ws + 42205248);    // alias pts4 (dead)
    float*    sigma    = (float*)(ws + 43254784);

    prep_kernel<<<NQ / 256, 256, 0, stream>>>(xyz, pts4, flag_cnt);
    knn_select_kernel<<<BB * 16 * NSLICE, 256, 0, stream>>>(pts4, val_buf);
    knn_merge_kernel<<<NQ / 64, 64, 0, stream>>>(val_buf, idx_buf,
                                                 flag_list, flag_cnt);
    knn_fallback_kernel<<<256, 256, 0, stream>>>(xyz, flag_list, flag_cnt,
                                                 idx_buf);
    gather_minmax_kernel<<<NQ / 4, 256, 0, stream>>>(feats, idx_buf, mx_buf,
                                                     mn_buf, partials);
    sigma_kernel<<<1, 1024, 0, stream>>>(partials, sigma);
    finalize_kernel<<<(NQ * CC) / 256, 256, 0, stream>>>(mx_buf, mn_buf, alpha,
                                                         beta, sigma, out);
}

// Round 11
// 336.032 us; speedup vs baseline: 1.0865x; 1.0096x over previous
//
#include <hip/hip_runtime.h>
#include <float.h>

#define BB 16
#define NN 4096
#define CC 64
#define KNN 32
#define NSLICE 16   // select slices per query
#define SSZ 256     // NN / NSLICE
#define CKEEP 8     // kept per slice
#define NQ 65536

// ===========================================================================
// KNN via packed-key select (R13 structure, measured-best) + R20 harvest of
// non-select time: prep folded into select, merge head-prefetch (hides the
// 1-wave/SIMD dependent-LDS stall), gather 2-queries/wave float2.
// Reference arithmetic VARIANT V2:
//   dot = fma(z,z', fma(y,y', x*x'));  xx = ((x*x + y*y) + z*z)  [rn, no fma]
//   pd  = fma(2, dot, -qxx) - xx_c    [== ((dot+dot)-qxx)-xx_c bitwise]
//   key = (~bits(min(pd,0)) & 0xFFFFF000) | (4095 - idx)
// Clamp safety: boundary collisions have equal 20-bit prefixes ->
// certificate (a) flags -> exact fallback. Certificates: (a) strict 20-bit
// separation at rank 32/33, (b) slice exhaustion (8th kept >= key33).
// Violations -> compacted flag list -> exact wave-per-query radix fallback
// (full-precision keys, exact tie-by-lowest-index). Correct at any flag
// rate. Merge prefetch: heads keep (v=current, w=next) in registers; the
// LDS read for the new w issues at pick time and is consumed only at that
// head's NEXT pick -- same pick sequence, bit-identical output.
// ===========================================================================

__device__ __forceinline__ int lane_rank(unsigned long long m) {
    return __builtin_amdgcn_mbcnt_hi((unsigned)(m >> 32),
           __builtin_amdgcn_mbcnt_lo((unsigned)m, 0u));
}

__device__ __forceinline__ unsigned med3u(unsigned a, unsigned b, unsigned c) {
    unsigned d;
    asm("v_med3_u32 %0, %1, %2, %3" : "=v"(d) : "v"(a), "v"(b), "v"(c));
    return d;
}

// 8-deep descending insert on u32 keys (h00 >= h01 >= ... >= h07)
#define UCHAIN8 \
  h07=med3u(ky,h07,h06); h06=med3u(ky,h06,h05); h05=med3u(ky,h05,h04); \
  h04=med3u(ky,h04,h03); h03=med3u(ky,h03,h02); h02=med3u(ky,h02,h01); \
  h01=med3u(ky,h01,h00); h00=(h00>ky)?h00:ky;

// --------------------------------------------------------------------------
// A: select (prep folded in). grid 4096 = (b<<8)|(g<<4)|s, 256 thr.
// Stage computes (x,y,z,xx) from raw xyz (V2 rn formula, bit-identical to
// the old prep). Block 0 zeroes flag_cnt (ordered before merge).
// --------------------------------------------------------------------------
__global__ __launch_bounds__(256) void knn_select_kernel(
        const float* __restrict__ xyz, unsigned* __restrict__ val_buf,
        int* __restrict__ flag_cnt) {
#pragma clang fp contract(off)
    __shared__ float4 pts[SSZ];
    const int tid = threadIdx.x;
    const int blk = blockIdx.x;
    if (blk == 0 && tid == 0) flag_cnt[0] = 0;
    const int s = blk & 15;
    const int g = (blk >> 4) & 15;
    const int b = blk >> 8;
    const float* xb = xyz + (size_t)b * (3 * NN);

    {
        const int i = (s << 8) | tid;
        float x = xb[i], y = xb[NN + i], z = xb[2 * NN + i];
        float xx = ((x * x) + (y * y)) + (z * z);  // rn (contract off)
        pts[tid] = make_float4(x, y, z, xx);
    }
    const int q = (g << 8) | tid;
    const float qx = xb[q], qy = xb[NN + q], qz = xb[2 * NN + q];
    const float nqxx = -(((qx * qx) + (qy * qy)) + (qz * qz));
    __syncthreads();

    unsigned h00=0,h01=0,h02=0,h03=0,h04=0,h05=0,h06=0,h07=0;
    const unsigned ibase = 4095u - (unsigned)(s << 8);  // idxterm = ibase - j
#pragma unroll 4
    for (int j = 0; j < SSZ; ++j) {
        float4 cp = pts[j];
        float dot = __builtin_fmaf(qz, cp.z, __builtin_fmaf(qy, cp.y, qx * cp.x));
        float pd = __builtin_fmaf(2.0f, dot, nqxx) - cp.w;
        pd = fminf(pd, 0.0f);                  // all pd <= 0 -> mono = ~u
        unsigned ky = (~__float_as_uint(pd) & 0xFFFFF000u)
                      | (ibase - (unsigned)j);
        UCHAIN8
    }

    const int qg = (b << 12) | q;
    unsigned* vp = val_buf + (size_t)(s * CKEEP) * NQ + qg;  // desc t=0..7
#define ST(t, ht) vp[(size_t)(t) * NQ] = ht;
    ST(0,h00) ST(1,h01) ST(2,h02) ST(3,h03)
    ST(4,h04) ST(5,h05) ST(6,h06) ST(7,h07)
#undef ST
}

// --------------------------------------------------------------------------
// B: merge. 64-thr blocks; stage 16x8=128 keys/query to LDS (stride 129 --
// the +1 slot also makes the speculative my[base+8] prefetch read safely
// in-bounds); 33-step 16-head merge with (v,w) register prefetch. First 32
// picks -> idx_out (idx = 4095 - (key&4095)). Certificates -> flag list.
// --------------------------------------------------------------------------
__global__ __launch_bounds__(64) void knn_merge_kernel(
        const unsigned* __restrict__ val_buf, int* __restrict__ idx_out,
        int* __restrict__ flag_list, int* __restrict__ flag_cnt) {
    __shared__ unsigned lv[64 * 129];  // 33 KB
    const int tid = threadIdx.x;
    const int qg = blockIdx.x * 64 + tid;
    unsigned* my = lv + tid * 129;
    for (int t = 0; t < 128; ++t) my[t] = val_buf[(size_t)t * NQ + qg];

    int p0=0,p1=0,p2=0,p3=0,p4=0,p5=0,p6=0,p7=0,
        p8=0,p9=0,p10=0,p11=0,p12=0,p13=0,p14=0,p15=0;
    unsigned v0 =my[0],  w0 =my[1];   unsigned v1 =my[8],  w1 =my[9];
    unsigned v2 =my[16], w2 =my[17];  unsigned v3 =my[24], w3 =my[25];
    unsigned v4 =my[32], w4 =my[33];  unsigned v5 =my[40], w5 =my[41];
    unsigned v6 =my[48], w6 =my[49];  unsigned v7 =my[56], w7 =my[57];
    unsigned v8 =my[64], w8 =my[65];  unsigned v9 =my[72], w9 =my[73];
    unsigned v10=my[80], w10=my[81];  unsigned v11=my[88], w11=my[89];
    unsigned v12=my[96], w12=my[97];  unsigned v13=my[104],w13=my[105];
    unsigned v14=my[112],w14=my[113]; unsigned v15=my[120],w15=my[121];
    int* outp = idx_out + (size_t)qg * KNN;
    unsigned key32 = 0u, key33 = 0u;
    for (int step = 0; step < 33; ++step) {
        unsigned best = v0; int bp = 0;
        if (v1  > best) { best = v1;  bp = 1; }
        if (v2  > best) { best = v2;  bp = 2; }
        if (v3  > best) { best = v3;  bp = 3; }
        if (v4  > best) { best = v4;  bp = 4; }
        if (v5  > best) { best = v5;  bp = 5; }
        if (v6  > best) { best = v6;  bp = 6; }
        if (v7  > best) { best = v7;  bp = 7; }
        if (v8  > best) { best = v8;  bp = 8; }
        if (v9  > best) { best = v9;  bp = 9; }
        if (v10 > best) { best = v10; bp = 10; }
        if (v11 > best) { best = v11; bp = 11; }
        if (v12 > best) { best = v12; bp = 12; }
        if (v13 > best) { best = v13; bp = 13; }
        if (v14 > best) { best = v14; bp = 14; }
        if (v15 > best) { best = v15; bp = 15; }
        if (step == 32) { key33 = best; break; }
        outp[step] = 4095 - (int)(best & 4095u);
        if (step == 31) key32 = best;
        // pick: v <- w; prefetch new w (consumed only at this head's next
        // pick, >= one full compare tree away -> LDS latency hidden).
        if      (bp==0)  { v0 =w0;  ++p0;  w0  = (p0 <7)?my[p0 +1]    :0u; }
        else if (bp==1)  { v1 =w1;  ++p1;  w1  = (p1 <7)?my[8+p1 +1]  :0u; }
        else if (bp==2)  { v2 =w2;  ++p2;  w2  = (p2 <7)?my[16+p2+1]  :0u; }
        else if (bp==3)  { v3 =w3;  ++p3;  w3  = (p3 <7)?my[24+p3+1]  :0u; }
        else if (bp==4)  { v4 =w4;  ++p4;  w4  = (p4 <7)?my[32+p4+1]  :0u; }
        else if (bp==5)  { v5 =w5;  ++p5;  w5  = (p5 <7)?my[40+p5+1]  :0u; }
        else if (bp==6)  { v6 =w6;  ++p6;  w6  = (p6 <7)?my[48+p6+1]  :0u; }
        else if (bp==7)  { v7 =w7;  ++p7;  w7  = (p7 <7)?my[56+p7+1]  :0u; }
        else if (bp==8)  { v8 =w8;  ++p8;  w8  = (p8 <7)?my[64+p8+1]  :0u; }
        else if (bp==9)  { v9 =w9;  ++p9;  w9  = (p9 <7)?my[72+p9+1]  :0u; }
        else if (bp==10) { v10=w10; ++p10; w10 = (p10<7)?my[80+p10+1] :0u; }
        else if (bp==11) { v11=w11; ++p11; w11 = (p11<7)?my[88+p11+1] :0u; }
        else if (bp==12) { v12=w12; ++p12; w12 = (p12<7)?my[96+p12+1] :0u; }
        else if (bp==13) { v13=w13; ++p13; w13 = (p13<7)?my[104+p13+1]:0u; }
        else if (bp==14) { v14=w14; ++p14; w14 = (p14<7)?my[112+p14+1]:0u; }
        else             { v15=w15; ++p15; w15 = (p15<7)?my[120+p15+1]:0u; }
    }

    // certificates: (a) strict 20-bit separation at the 32/33 boundary;
    // (b) every slice's 8th kept key < key33 (merge saw the true top-33).
    bool flag = ((key32 >> 12) == (key33 >> 12));
    for (int sl = 0; sl < 16; ++sl)
        flag = flag || (my[sl * 8 + 7] >= key33);
    if (flag) {
        int pos = atomicAdd(flag_cnt, 1);
        flag_list[pos] = qg;
    }
}

// --------------------------------------------------------------------------
// B2: exact fallback, wave-per-query over the compacted flag list.
// Full-precision mono keys in 64 statically-indexed VGPRs; 32-step radix
// select -> exact 32nd key; indices via ballot compaction (index order,
// eq-ties take first `budget` -- exact reference tie semantics).
// --------------------------------------------------------------------------
__global__ __launch_bounds__(256) void knn_fallback_kernel(
        const float* __restrict__ xyz, const int* __restrict__ flag_list,
        const int* __restrict__ flag_cnt, int* __restrict__ idx_out) {
#pragma clang fp contract(off)
    const int nflag = flag_cnt[0];
    const int lane = threadIdx.x & 63;
    const int wid = (blockIdx.x * 256 + threadIdx.x) >> 6;
    const int nw = (gridDim.x * 256) >> 6;
    for (int w = wid; w < nflag; w += nw) {
        const int qg = flag_list[w];
        const int b = qg >> 12;
        const int q = qg & (NN - 1);
        const float* xb = xyz + (size_t)b * (3 * NN);
        const float qx = xb[q], qy = xb[NN + q], qz = xb[2 * NN + q];
        const float qxx = ((qx * qx) + (qy * qy)) + (qz * qz);
        const float nqxx = -qxx;

        unsigned key[64];
#pragma unroll
        for (int i = 0; i < 64; ++i) {
            const int j = (i << 6) | lane;
            float x = xb[j], y = xb[NN + j], z = xb[2 * NN + j];
            float xxc = ((x * x) + (y * y)) + (z * z);
            float dot = __builtin_fmaf(qz, z, __builtin_fmaf(qy, y, qx * x));
            float pd = __builtin_fmaf(2.0f, dot, nqxx) - xxc;
            unsigned u = __float_as_uint(pd);
            key[i] = u ^ (unsigned)(((int)u >> 31) | 0x80000000);
        }

        // largest t with #{key >= t} >= 32  ==  32nd-largest key
        unsigned cur = 0u;
        for (int bit = 31; bit >= 0; --bit) {
            const unsigned cand = cur | (1u << bit);
            int c = 0;
#pragma unroll
            for (int i = 0; i < 64; ++i) c += (key[i] >= cand) ? 1 : 0;
#pragma unroll
            for (int o = 32; o >= 1; o >>= 1) c += __shfl_xor(c, o, 64);
            if (c >= 32) cur = cand;  // uniform after butterfly
        }

        // exact gt/eq totals
        int ge = 0;
#pragma unroll
        for (int i = 0; i < 64; ++i) {
            ge += (key[i] > cur) ? 1 : 0;
            ge += (key[i] == cur) ? 0x10000 : 0;
        }
#pragma unroll
        for (int o = 32; o >= 1; o >>= 1) ge += __shfl_xor(ge, o, 64);
        const int gt_total = ge & 0xFFFF;
        const int budget = min(ge >> 16, 32 - gt_total);

        int* outp = idx_out + (size_t)qg * KNN;
        int slot = 0, neq = 0;
#pragma unroll
        for (int i = 0; i < 64; ++i) {
            const bool isgt = key[i] > cur;
            const bool iseq = key[i] == cur;
            const unsigned long long mgt = __ballot(isgt);
            const unsigned long long meq = __ballot(iseq);
            if (isgt) outp[slot + lane_rank(mgt)] = (i << 6) | lane;
            if (iseq) {
                const int r = neq + lane_rank(meq);
                if (r < budget) outp[gt_total + r] = (i << 6) | lane;
            }
            slot += __builtin_popcountll(mgt);
            neq += __builtin_popcountll(meq);
        }
    }
}

// --------------------------------------------------------------------------
// gather: 2 queries per wave (32 lanes x 2 channels via float2). 8 queries
// per 256-thr block -> NQ/8 blocks, partials[8192]. mx/mn bits identical
// (same fmax/fmin values); ss summation order changes by ~1e-16 relative.
// --------------------------------------------------------------------------
__global__ __launch_bounds__(256) void gather_minmax_kernel(
        const float* __restrict__ feats, const int* __restrict__ idx_in,
        float* __restrict__ mx_buf, float* __restrict__ mn_buf,
        double* __restrict__ partials) {
    const int tid = threadIdx.x;
    const int qw = tid >> 5;          // 0..7: query within block
    const int lane32 = tid & 31;      // channel pair index
    const int q = blockIdx.x * 8 + qw;
    const int b = q >> 12;
    const float2* fb2 = (const float2*)(feats + (size_t)b * (NN * CC));
    const int ql = q & (NN - 1);
    const float2 c2 = fb2[(size_t)ql * 32 + lane32];
    const int* ip = idx_in + (size_t)q * KNN;

    float mx0 = -FLT_MAX, mn0 = FLT_MAX, mx1 = -FLT_MAX, mn1 = FLT_MAX;
    double ss = 0.0;
#pragma unroll 4
    for (int k = 0; k < KNN; ++k) {
        int nb = ip[k];
        float2 v = fb2[(size_t)nb * 32 + lane32];
        float o0 = v.x - c2.x;
        float o1 = v.y - c2.y;
        mx0 = fmaxf(mx0, o0); mn0 = fminf(mn0, o0);
        mx1 = fmaxf(mx1, o1); mn1 = fminf(mn1, o1);
        double d0 = (double)o0, d1 = (double)o1;
        ss = fma(d0, d0, ss);
        ss = fma(d1, d1, ss);
    }
    ((float2*)mx_buf)[(size_t)q * 32 + lane32] = make_float2(mx0, mx1);
    ((float2*)mn_buf)[(size_t)q * 32 + lane32] = make_float2(mn0, mn1);

#pragma unroll
    for (int o = 16; o >= 1; o >>= 1) ss += __shfl_down(ss, o, 64);
    __shared__ double wsum[8];
    if (lane32 == 0) wsum[qw] = ss;
    __syncthreads();
    if (tid == 0) {
        double t = ((wsum[0] + wsum[1]) + (wsum[2] + wsum[3]))
                 + ((wsum[4] + wsum[5]) + (wsum[6] + wsum[7]));
        partials[blockIdx.x] = t;
    }
}

__global__ __launch_bounds__(1024) void sigma_kernel(const double* __restrict__ partials,
                                                     float* __restrict__ sigma) {
    __shared__ double red[1024];
    double s = 0.0;
    for (int i = threadIdx.x; i < 8192; i += 1024) s += partials[i];
    red[threadIdx.x] = s;
    __syncthreads();
    for (int o = 512; o >= 1; o >>= 1) {
        if (threadIdx.x < o) red[threadIdx.x] += red[threadIdx.x + o];
        __syncthreads();
    }
    if (threadIdx.x == 0) sigma[0] = (float)(red[0] * (1.0 / 134217728.0));
}

__global__ __launch_bounds__(256) void finalize_kernel(
        const float* __restrict__ mx_buf, const float* __restrict__ mn_buf,
        const float* __restrict__ alpha, const float* __restrict__ beta,
        const float* __restrict__ sigma, float* __restrict__ out) {
#pragma clang fp contract(off)
    const int e = blockIdx.x * 256 + threadIdx.x;
    const int c = e & (CC - 1);
    const float s = sigma[0] + 1e-5f;
    const float a = alpha[c];
    const float bt = beta[c];
    const float off = (a >= 0.f) ? mx_buf[e] : mn_buf[e];
    const float t = off / s;
    out[e] = (t * a) + bt;
}

extern "C" void kernel_launch(void* const* d_in, const int* in_sizes, int n_in,
                              void* d_out, int out_size, void* d_ws, size_t ws_size,
                              hipStream_t stream) {
    (void)in_sizes; (void)n_in; (void)out_size; (void)ws_size;
    const float* xyz   = (const float*)d_in[0];  // [16,3,4096]
    const float* feats = (const float*)d_in[1];  // [16,4096,64]
    const float* alpha = (const float*)d_in[2];  // [64]
    const float* beta  = (const float*)d_in[3];  // [64]
    float* out = (float*)d_out;                  // [16,4096,64]

    char* ws = (char*)d_ws;
    // Lifetimes:
    //   val_buf   [0, 33,554,432)          select->merge(read); dead after.
    //   mx/mn     alias val region          written by gather (post-merge).
    //   idx_buf   [33,554,432, 41,943,040)  merge/fallback write, gather reads.
    //   flag_list [41,943,040, +256 KB)     merge->fallback.
    //   flag_cnt  42,205,184 (4 B)
    //   partials  [42,205,248, +64 KB)      gather->sigma.
    //   sigma     43,254,784
    unsigned* val_buf  = (unsigned*)ws;
    float*    mx_buf   = (float*)ws;                  // [0, 16.78M)
    float*    mn_buf   = (float*)(ws + 16777216);     // [16.78M, 33.55M)
    int*      idx_buf  = (int*)(ws + 33554432);
    int*      flag_list= (int*)(ws + 41943040);
    int*      flag_cnt = (int*)(ws + 42205184);
    double*   partials = (double*)(ws + 42205248);
    float*    sigma    = (float*)(ws + 43254784);

    knn_select_kernel<<<BB * 16 * NSLICE, 256, 0, stream>>>(xyz, val_buf,
                                                            flag_cnt);
    knn_merge_kernel<<<NQ / 64, 64, 0, stream>>>(val_buf, idx_buf,
                                                 flag_list, flag_cnt);
    knn_fallback_kernel<<<256, 256, 0, stream>>>(xyz, flag_list, flag_cnt,
                                                 idx_buf);
    gather_minmax_kernel<<<NQ / 8, 256, 0, stream>>>(feats, idx_buf, mx_buf,
                                                     mn_buf, partials);
    sigma_kernel<<<1, 1024, 0, stream>>>(partials, sigma);
    finalize_kernel<<<(NQ * CC) / 256, 256, 0, stream>>>(mx_buf, mn_buf, alpha,
                                                         beta, sigma, out);
}